// Round 9
// baseline (436.072 us; speedup 1.0000x reference)
//
#include <hip/hip_runtime.h>

namespace {
constexpr int E_N  = 131072;
constexpr int FEA  = 256;
constexpr int RAD  = 64;
constexpr int HID  = 128;
constexpr int WN   = 256;
constexpr int EPB  = 64;    // edges per block
constexpr int NT   = 256;   // 4 waves
constexpr int ASTR = 132;   // act stride: 132%32=4 -> conflict-light, 16B rows
constexpr int SMEMF = EPB * ASTR;   // 8448 floats = 33792 B, time-aliased buffer
}

typedef float float2v __attribute__((ext_vector_type(2)));

// One VOP3P packed FMA: {d.x,d.y} = {a.x*b.x+c.x, a.y*b.y+c.y}
__device__ __forceinline__ float2v pkfma(float2v a, float2v b, float2v c) {
    float2v d;
    asm("v_pk_fma_f32 %0, %1, %2, %3" : "=v"(d) : "v"(a), "v"(b), "v"(c));
    return d;
}
__device__ __forceinline__ float2v mk2(float a, float b) {
    float2v r; r.x = a; r.y = b; return r;
}

struct R8 { float a0[8], a1[8], a2[8], a3[8]; };

__global__ __launch_bounds__(NT, 4)
void fused_mlp_dtp(
    const float* __restrict__ fea_a, const float* __restrict__ vec_a,
    const float* __restrict__ len_a, const float* __restrict__ W1_a,
    const float* __restrict__ b1_a,  const float* __restrict__ g_a,
    const float* __restrict__ be_a,  const float* __restrict__ W2_a,
    const float* __restrict__ fea_b, const float* __restrict__ vec_b,
    const float* __restrict__ len_b, const float* __restrict__ W1_b,
    const float* __restrict__ b1_b,  const float* __restrict__ g_b,
    const float* __restrict__ be_b,  const float* __restrict__ W2_b,
    float* __restrict__ out)
{
    // Time-aliased LDS (33792 B):
    //   phases 1-2:  len f32[64][64]   in [0, 16K)
    //   phases 2b-4: act f32[64][132]  in [0, 33792)
    //   epilogue:    stage 4x1536 f32  in [0, 24576)
    __shared__ __align__(16) float smem[SMEMF];

    const int pipe = blockIdx.y;
    const float* __restrict__ fea = pipe ? fea_b : fea_a;
    const float* __restrict__ vec = pipe ? vec_b : vec_a;
    const float* __restrict__ len = pipe ? len_b : len_a;
    const float* __restrict__ W1  = pipe ? W1_b  : W1_a;
    const float* __restrict__ b1  = pipe ? b1_b  : b1_a;
    const float* __restrict__ g   = pipe ? g_b   : g_a;
    const float* __restrict__ be  = pipe ? be_b  : be_a;
    const float* __restrict__ W2  = pipe ? W2_b  : W2_a;
    float* __restrict__ outp = out + (size_t)pipe * (size_t)E_N * FEA;

    const int t    = threadIdx.x;
    const int lane = t & 63;
    const int wv_  = t >> 6;
    const long e0  = (long)blockIdx.x * EPB;

    // ---------- Phase 1: stage len tile [64][64] into smem[0..4096) ----------
    {
        const float4* __restrict__ src = (const float4*)(len + e0 * RAD);
        float4* dst = (float4*)smem;
        #pragma unroll
        for (int i = 0; i < (EPB * RAD / 4) / NT; ++i)
            dst[t + i * NT] = src[t + i * NT];
    }
    __syncthreads();

    // ---------- Phase 2: h = len @ W1 + b1, accumulate in regs (pk over k) ---
    float2v acc2p[8][4];
    const int c0 = (t & 31) * 4;        // col block 0..124
    const int eb = (t >> 5) * 8;        // edge block 0..56
    {
        #pragma unroll
        for (int i = 0; i < 8; ++i)
            #pragma unroll
            for (int j = 0; j < 4; ++j) { acc2p[i][j].x = 0.f; acc2p[i][j].y = 0.f; }

        for (int kg = 0; kg < RAD / 4; ++kg) {
            const float4 w0 = *(const float4*)(W1 + (size_t)(kg*4 + 0) * HID + c0);
            const float4 w1 = *(const float4*)(W1 + (size_t)(kg*4 + 1) * HID + c0);
            const float4 w2 = *(const float4*)(W1 + (size_t)(kg*4 + 2) * HID + c0);
            const float4 w3 = *(const float4*)(W1 + (size_t)(kg*4 + 3) * HID + c0);
            const float2v wp0[4] = { mk2(w0.x,w1.x), mk2(w0.y,w1.y),
                                     mk2(w0.z,w1.z), mk2(w0.w,w1.w) };
            const float2v wp1[4] = { mk2(w2.x,w3.x), mk2(w2.y,w3.y),
                                     mk2(w2.z,w3.z), mk2(w2.w,w3.w) };
            #pragma unroll
            for (int i = 0; i < 8; ++i) {
                const float4 lv = *(const float4*)(&smem[(eb + i) * RAD + kg * 4]);
                const float2v a01 = mk2(lv.x, lv.y);
                const float2v a23 = mk2(lv.z, lv.w);
                #pragma unroll
                for (int c = 0; c < 4; ++c) {
                    acc2p[i][c] = pkfma(a01, wp0[c], acc2p[i][c]);
                    acc2p[i][c] = pkfma(a23, wp1[c], acc2p[i][c]);
                }
            }
        }
    }
    __syncthreads();   // all len reads complete; region becomes act

    // ---------- Phase 2b: write h into act[64][132] ----------
    {
        const float4 bv = *(const float4*)(b1 + c0);
        #pragma unroll
        for (int i = 0; i < 8; ++i) {
            const float4 o = make_float4(acc2p[i][0].x + acc2p[i][0].y + bv.x,
                                         acc2p[i][1].x + acc2p[i][1].y + bv.y,
                                         acc2p[i][2].x + acc2p[i][2].y + bv.z,
                                         acc2p[i][3].x + acc2p[i][3].y + bv.w);
            *(float4*)(&smem[(eb + i) * ASTR + c0]) = o;
        }
    }
    __syncthreads();

    // ---------- Phase 3: LayerNorm + SiLU in place ----------
    {
        const int e = t >> 2;               // 0..63
        const int q = t & 3;                // 4 threads/edge, 32 cols each
        float* __restrict__ row = &smem[e * ASTR + q * 32];
        float hv[32];
        float s = 0.f, s2 = 0.f;
        #pragma unroll
        for (int j = 0; j < 8; ++j) {
            const float4 v = *(const float4*)(row + 4 * j);
            hv[4*j+0] = v.x; hv[4*j+1] = v.y; hv[4*j+2] = v.z; hv[4*j+3] = v.w;
            s  += v.x + v.y + v.z + v.w;
            s2 += v.x*v.x + v.y*v.y + v.z*v.z + v.w*v.w;
        }
        s  += __shfl_xor(s, 1);  s  += __shfl_xor(s, 2);
        s2 += __shfl_xor(s2, 1); s2 += __shfl_xor(s2, 2);
        const float mu  = s * (1.0f / HID);
        float var = s2 * (1.0f / HID) - mu * mu;
        var = fmaxf(var, 0.0f);
        const float inv = rsqrtf(var + 1e-5f);
        const float4* __restrict__ gr  = (const float4*)(g  + q * 32);
        const float4* __restrict__ ber = (const float4*)(be + q * 32);
        #pragma unroll
        for (int j = 0; j < 8; ++j) {
            const float4 gv = gr[j];
            const float4 bv = ber[j];
            const float h0 = (hv[4*j+0] - mu) * inv * gv.x + bv.x;
            const float h1 = (hv[4*j+1] - mu) * inv * gv.y + bv.y;
            const float h2 = (hv[4*j+2] - mu) * inv * gv.z + bv.z;
            const float h3 = (hv[4*j+3] - mu) * inv * gv.w + bv.w;
            float4 o;
            o.x = h0 / (1.0f + __expf(-h0));
            o.y = h1 / (1.0f + __expf(-h1));
            o.z = h2 / (1.0f + __expf(-h2));
            o.w = h3 / (1.0f + __expf(-h3));
            *(float4*)(row + 4 * j) = o;
        }
    }
    __syncthreads();

    // ---------- Phase 4: w = silu @ W2 as TWO 8-edge passes (64 live acc) ----
    const int u = lane;
    auto gemm8 = [&](int ebase8) -> R8 {
        float2v acc2[8][4];
        #pragma unroll
        for (int i = 0; i < 8; ++i)
            #pragma unroll
            for (int c = 0; c < 4; ++c) { acc2[i][c].x = 0.f; acc2[i][c].y = 0.f; }

        for (int kg = 0; kg < HID / 4; ++kg) {
            // load W2 elements directly into pair halves (no pack movs)
            const float* __restrict__ Wr0 = W2 + (size_t)(kg*4 + 0) * WN + u;
            const float* __restrict__ Wr1 = W2 + (size_t)(kg*4 + 1) * WN + u;
            const float* __restrict__ Wr2 = W2 + (size_t)(kg*4 + 2) * WN + u;
            const float* __restrict__ Wr3 = W2 + (size_t)(kg*4 + 3) * WN + u;
            float2v wp0[4], wp1[4];
            #pragma unroll
            for (int c = 0; c < 4; ++c) {
                wp0[c].x = Wr0[c * 64];   // k even
                wp0[c].y = Wr1[c * 64];   // k odd
                wp1[c].x = Wr2[c * 64];
                wp1[c].y = Wr3[c * 64];
            }
            #pragma unroll
            for (int i = 0; i < 8; ++i) {
                const float4 av = *(const float4*)(&smem[(ebase8 + i) * ASTR + kg * 4]);
                const float2v a01 = mk2(av.x, av.y);
                const float2v a23 = mk2(av.z, av.w);
                #pragma unroll
                for (int c = 0; c < 4; ++c) {
                    acc2[i][c] = pkfma(a01, wp0[c], acc2[i][c]);
                    acc2[i][c] = pkfma(a23, wp1[c], acc2[i][c]);
                }
            }
        }
        R8 r;
        #pragma unroll
        for (int i = 0; i < 8; ++i) {
            r.a0[i] = acc2[i][0].x + acc2[i][0].y;
            r.a1[i] = acc2[i][1].x + acc2[i][1].y;
            r.a2[i] = acc2[i][2].x + acc2[i][2].y;
            r.a3[i] = acc2[i][3].x + acc2[i][3].y;
        }
        return r;
    };
    const R8 rA = gemm8(wv_ * 16 + 0);
    const R8 rB = gemm8(wv_ * 16 + 8);
    __syncthreads();   // all act reads done; region becomes epilogue stage

    // ---------- Epilogue: DTP per 8-edge chunk; out0 direct, out1 staged ----
    const float c2 = 0.70710678118654752f;   // 1/sqrt(2)
    const float c3 = 0.40824829046386302f;   // 1/sqrt(6)
    auto epi8 = [&](int p, const R8& r) {
        const long eb8 = e0 + wv_ * 16 + p * 8;
        float* sStage = smem + wv_ * 1536;   // 6 KB per wave, disjoint
        #pragma unroll
        for (int m = 0; m < 8; ++m) {
            const long e = eb8 + m;
            const float4 y = *(const float4*)(vec + e * 4);
            const float* __restrict__ fr = fea + e * (size_t)FEA;
            const float x0  = fr[u];
            const float x1a = fr[64 + 3*u + 0];
            const float x1b = fr[64 + 3*u + 1];
            const float x1c = fr[64 + 3*u + 2];
            const float w1 = r.a0[m], w2 = r.a1[m], w3 = r.a2[m], w4 = r.a3[m];
            const float dot = x1a*y.y + x1b*y.z + x1c*y.w;
            outp[e * (size_t)FEA + u] = w1*x0*y.x*c2 + w4*dot*c3;  // 256B/instr
            sStage[m*192 + 3*u + 0] = (w2*x0*y.y + w3*x1a*y.x) * c2;
            sStage[m*192 + 3*u + 1] = (w2*x0*y.z + w3*x1b*y.x) * c2;
            sStage[m*192 + 3*u + 2] = (w2*x0*y.w + w3*x1c*y.x) * c2;
        }
        __syncthreads();   // stage complete (convergent: all waves both calls)
        #pragma unroll
        for (int rr = 0; rr < 6; ++rr) {
            const int flat = rr * 256 + u * 4;   // 0..1532, 16B aligned
            const int eloc = flat / 192;         // 0..7
            const int pos  = flat % 192;
            const float4 v = *(const float4*)(&sStage[flat]);
            *(float4*)(&outp[(eb8 + eloc) * (size_t)FEA + 64 + pos]) = v;
        }
        __syncthreads();   // drain complete before next chunk overwrites
    };
    epi8(0, rA);
    epi8(1, rB);
}

extern "C" void kernel_launch(void* const* d_in, const int* in_sizes, int n_in,
                              void* d_out, int out_size, void* d_ws, size_t ws_size,
                              hipStream_t stream) {
    (void)in_sizes; (void)n_in; (void)d_ws; (void)ws_size; (void)out_size;
    const float* fea_a = (const float*)d_in[0];
    const float* vec_a = (const float*)d_in[1];
    const float* len_a = (const float*)d_in[2];
    const float* W1_a  = (const float*)d_in[3];
    const float* b1_a  = (const float*)d_in[4];
    const float* g_a   = (const float*)d_in[5];
    const float* be_a  = (const float*)d_in[6];
    const float* W2_a  = (const float*)d_in[7];
    const float* fea_b = (const float*)d_in[8];
    const float* vec_b = (const float*)d_in[9];
    const float* len_b = (const float*)d_in[10];
    const float* W1_b  = (const float*)d_in[11];
    const float* b1_b  = (const float*)d_in[12];
    const float* g_b   = (const float*)d_in[13];
    const float* be_b  = (const float*)d_in[14];
    const float* W2_b  = (const float*)d_in[15];
    float* out = (float*)d_out;

    dim3 grid(E_N / EPB, 2);
    dim3 block(NT);
    hipLaunchKernelGGL(fused_mlp_dtp, grid, block, 0, stream,
                       fea_a, vec_a, len_a, W1_a, b1_a, g_a, be_a, W2_a,
                       fea_b, vec_b, len_b, W1_b, b1_b, g_b, be_b, W2_b,
                       out);
}

// Round 10
// 320.639 us; speedup vs baseline: 1.3600x; 1.3600x over previous
//
#include <hip/hip_runtime.h>

namespace {
constexpr int E_N  = 131072;
constexpr int FEA  = 256;
constexpr int RAD  = 64;
constexpr int HID  = 128;
constexpr int WN   = 256;
constexpr int EPB  = 64;    // edges per block
constexpr int NT   = 256;   // 4 waves
constexpr int ASTR = 132;   // act stride (floats), 16B-aligned rows
constexpr int SMEMF = EPB * ASTR;   // 8448 floats = 33792 B time-aliased
}

typedef float float2v __attribute__((ext_vector_type(2)));

// VOP3P packed FMA, src0 word-broadcast via op_sel:
//   lo-bcast: d = {s0.x*s1.x + c.x, s0.x*s1.y + c.y}
__device__ __forceinline__ float2v pkfma_lo(float2v a, float2v b, float2v c) {
    float2v d;
    asm("v_pk_fma_f32 %0, %1, %2, %3 op_sel:[0,0,0] op_sel_hi:[0,1,1]"
        : "=v"(d) : "v"(a), "v"(b), "v"(c));
    return d;
}
//   hi-bcast: d = {s0.y*s1.x + c.x, s0.y*s1.y + c.y}
__device__ __forceinline__ float2v pkfma_hi(float2v a, float2v b, float2v c) {
    float2v d;
    asm("v_pk_fma_f32 %0, %1, %2, %3 op_sel:[1,0,0] op_sel_hi:[1,1,1]"
        : "=v"(d) : "v"(a), "v"(b), "v"(c));
    return d;
}

__global__ __launch_bounds__(NT, 4)
void fused_mlp_dtp(
    const float* __restrict__ fea_a, const float* __restrict__ vec_a,
    const float* __restrict__ len_a, const float* __restrict__ W1_a,
    const float* __restrict__ b1_a,  const float* __restrict__ g_a,
    const float* __restrict__ be_a,  const float* __restrict__ W2_a,
    const float* __restrict__ fea_b, const float* __restrict__ vec_b,
    const float* __restrict__ len_b, const float* __restrict__ W1_b,
    const float* __restrict__ b1_b,  const float* __restrict__ g_b,
    const float* __restrict__ be_b,  const float* __restrict__ W2_b,
    float* __restrict__ out)
{
    // Time-aliased LDS (33792 B):
    //   phases 1-2:  len f32[64][64] in [0,16K)
    //   phases 2b-4: act f32[64][132]
    //   epilogue:    stage 4 x 768 f32 in [0,12K)
    __shared__ __align__(16) float smem[SMEMF];

    const int pipe = blockIdx.y;
    const float* __restrict__ fea = pipe ? fea_b : fea_a;
    const float* __restrict__ vec = pipe ? vec_b : vec_a;
    const float* __restrict__ len = pipe ? len_b : len_a;
    const float* __restrict__ W1  = pipe ? W1_b  : W1_a;
    const float* __restrict__ b1  = pipe ? b1_b  : b1_a;
    const float* __restrict__ g   = pipe ? g_b   : g_a;
    const float* __restrict__ be  = pipe ? be_b  : be_a;
    const float* __restrict__ W2  = pipe ? W2_b  : W2_a;
    float* __restrict__ outp = out + (size_t)pipe * (size_t)E_N * FEA;

    const int t    = threadIdx.x;
    const int lane = t & 63;
    const int wv_  = t >> 6;
    const long e0  = (long)blockIdx.x * EPB;

    // ---------- Phase 1: stage len tile [64][64] ----------
    {
        const float4* __restrict__ src = (const float4*)(len + e0 * RAD);
        float4* dst = (float4*)smem;
        #pragma unroll
        for (int i = 0; i < (EPB * RAD / 4) / NT; ++i)
            dst[t + i * NT] = src[t + i * NT];
    }
    __syncthreads();

    // ---------- Phase 2: h = len @ W1 + b1, acc in regs (comp-pairs) --------
    const int c0 = (t & 31) * 4;        // col block 0..124
    const int eb = (t >> 5) * 8;        // edge block 0..56
    float2v accA[8], accB[8];           // cols (c0,c0+1) and (c0+2,c0+3)
    {
        #pragma unroll
        for (int i = 0; i < 8; ++i) { accA[i] = (float2v)0.f; accB[i] = (float2v)0.f; }

        for (int kg = 0; kg < RAD / 4; ++kg) {
            float4 w0 = *(const float4*)(W1 + (size_t)(kg*4 + 0) * HID + c0);
            float4 w1 = *(const float4*)(W1 + (size_t)(kg*4 + 1) * HID + c0);
            float4 w2 = *(const float4*)(W1 + (size_t)(kg*4 + 2) * HID + c0);
            float4 w3 = *(const float4*)(W1 + (size_t)(kg*4 + 3) * HID + c0);
            const float2v w0A = *(float2v*)&w0, w0B = *((float2v*)&w0 + 1);
            const float2v w1A = *(float2v*)&w1, w1B = *((float2v*)&w1 + 1);
            const float2v w2A = *(float2v*)&w2, w2B = *((float2v*)&w2 + 1);
            const float2v w3A = *(float2v*)&w3, w3B = *((float2v*)&w3 + 1);
            #pragma unroll
            for (int i = 0; i < 8; ++i) {
                float4 lv = *(const float4*)(&smem[(eb + i) * RAD + kg * 4]);
                const float2v lvA = *(float2v*)&lv;        // {k0, k1}
                const float2v lvB = *((float2v*)&lv + 1);  // {k2, k3}
                accA[i] = pkfma_lo(lvA, w0A, accA[i]);     // k0
                accB[i] = pkfma_lo(lvA, w0B, accB[i]);
                accA[i] = pkfma_hi(lvA, w1A, accA[i]);     // k1
                accB[i] = pkfma_hi(lvA, w1B, accB[i]);
                accA[i] = pkfma_lo(lvB, w2A, accA[i]);     // k2
                accB[i] = pkfma_lo(lvB, w2B, accB[i]);
                accA[i] = pkfma_hi(lvB, w3A, accA[i]);     // k3
                accB[i] = pkfma_hi(lvB, w3B, accB[i]);
            }
        }
    }
    __syncthreads();   // len reads complete; region becomes act

    // ---------- Phase 2b: write h into act[64][132] ----------
    {
        const float4 bv = *(const float4*)(b1 + c0);
        #pragma unroll
        for (int i = 0; i < 8; ++i) {
            const float4 o = make_float4(accA[i].x + bv.x, accA[i].y + bv.y,
                                         accB[i].x + bv.z, accB[i].y + bv.w);
            *(float4*)(&smem[(eb + i) * ASTR + c0]) = o;
        }
    }
    __syncthreads();

    // ---------- Phase 3: LayerNorm + SiLU in place ----------
    {
        const int e = t >> 2;               // 0..63
        const int q = t & 3;                // 4 threads/edge, 32 cols each
        float* __restrict__ row = &smem[e * ASTR + q * 32];
        float hv[32];
        float s = 0.f, s2 = 0.f;
        #pragma unroll
        for (int j = 0; j < 8; ++j) {
            const float4 v = *(const float4*)(row + 4 * j);
            hv[4*j+0] = v.x; hv[4*j+1] = v.y; hv[4*j+2] = v.z; hv[4*j+3] = v.w;
            s  += v.x + v.y + v.z + v.w;
            s2 += v.x*v.x + v.y*v.y + v.z*v.z + v.w*v.w;
        }
        s  += __shfl_xor(s, 1);  s  += __shfl_xor(s, 2);
        s2 += __shfl_xor(s2, 1); s2 += __shfl_xor(s2, 2);
        const float mu  = s * (1.0f / HID);
        float var = s2 * (1.0f / HID) - mu * mu;
        var = fmaxf(var, 0.0f);
        const float inv = rsqrtf(var + 1e-5f);
        const float4* __restrict__ gr  = (const float4*)(g  + q * 32);
        const float4* __restrict__ ber = (const float4*)(be + q * 32);
        #pragma unroll
        for (int j = 0; j < 8; ++j) {
            const float4 gv = gr[j];
            const float4 bv = ber[j];
            const float h0 = (hv[4*j+0] - mu) * inv * gv.x + bv.x;
            const float h1 = (hv[4*j+1] - mu) * inv * gv.y + bv.y;
            const float h2 = (hv[4*j+2] - mu) * inv * gv.z + bv.z;
            const float h3 = (hv[4*j+3] - mu) * inv * gv.w + bv.w;
            float4 o;
            o.x = h0 / (1.0f + __expf(-h0));
            o.y = h1 / (1.0f + __expf(-h1));
            o.z = h2 / (1.0f + __expf(-h2));
            o.w = h3 / (1.0f + __expf(-h3));
            *(float4*)(row + 4 * j) = o;
        }
    }
    __syncthreads();

    // ---------- Phase 4: w = silu @ W2 (comp-pair op_sel pk-FMA) ----------
    const int u   = lane;
    const int eb4 = wv_ * 16;
    float2v a01[16], a23[16];   // {comp0,comp1} and {comp2,comp3} per edge
    {
        #pragma unroll
        for (int i = 0; i < 16; ++i) { a01[i] = (float2v)0.f; a23[i] = (float2v)0.f; }

        for (int kg = 0; kg < HID / 4; ++kg) {
            const float* __restrict__ Wb = W2 + (size_t)(kg * 4) * WN + u;
            float2v p01[4], p23[4];       // per kk: {W[k][u],W[k][64+u]}, {W[k][128+u],W[k][192+u]}
            #pragma unroll
            for (int kk = 0; kk < 4; ++kk) {
                p01[kk].x = Wb[kk * WN];
                p01[kk].y = Wb[kk * WN + 64];
                p23[kk].x = Wb[kk * WN + 128];
                p23[kk].y = Wb[kk * WN + 192];
            }
            #pragma unroll
            for (int i = 0; i < 16; ++i) {
                float4 av = *(const float4*)(&smem[(eb4 + i) * ASTR + kg * 4]);
                const float2v avA = *(float2v*)&av;        // {k0, k1}
                const float2v avB = *((float2v*)&av + 1);  // {k2, k3}
                a01[i] = pkfma_lo(avA, p01[0], a01[i]);    // k0
                a23[i] = pkfma_lo(avA, p23[0], a23[i]);
                a01[i] = pkfma_hi(avA, p01[1], a01[i]);    // k1
                a23[i] = pkfma_hi(avA, p23[1], a23[i]);
                a01[i] = pkfma_lo(avB, p01[2], a01[i]);    // k2
                a23[i] = pkfma_lo(avB, p23[2], a23[i]);
                a01[i] = pkfma_hi(avB, p01[3], a01[i]);    // k3
                a23[i] = pkfma_hi(avB, p23[3], a23[i]);
            }
        }
    }
    __syncthreads();   // act reads done; region becomes epilogue stage

    // ---------- Epilogue: DTP; out0 direct, out1 via barriered LDS stage ----
    {
        const long ebase = e0 + wv_ * 16;
        float* sStage = smem + wv_ * 768;            // 3 KB per wave, disjoint
        const float c2 = 0.70710678118654752f;       // 1/sqrt(2)
        const float c3 = 0.40824829046386302f;       // 1/sqrt(6)

        for (int ch = 0; ch < 4; ++ch) {
            #pragma unroll
            for (int m = 0; m < 4; ++m) {
                const int i = ch * 4 + m;
                const long e = ebase + i;
                const float4 y = *(const float4*)(vec + e * 4);
                const float* __restrict__ fr = fea + e * (size_t)FEA;
                const float x0  = fr[u];
                const float x1a = fr[64 + 3*u + 0];
                const float x1b = fr[64 + 3*u + 1];
                const float x1c = fr[64 + 3*u + 2];
                const float w1 = a01[i].x, w2 = a01[i].y;
                const float w3 = a23[i].x, w4 = a23[i].y;
                const float dot = x1a*y.y + x1b*y.z + x1c*y.w;
                outp[e * (size_t)FEA + u] = w1*x0*y.x*c2 + w4*dot*c3;  // 256B/instr
                sStage[m*192 + 3*u + 0] = (w2*x0*y.y + w3*x1a*y.x) * c2;
                sStage[m*192 + 3*u + 1] = (w2*x0*y.z + w3*x1b*y.x) * c2;
                sStage[m*192 + 3*u + 2] = (w2*x0*y.w + w3*x1c*y.x) * c2;
            }
            __syncthreads();   // stage complete (convergent: all waves, all ch)
            #pragma unroll
            for (int r = 0; r < 3; ++r) {
                const int flat = r * 256 + u * 4;    // 0..764, 16B aligned
                const int eloc = flat / 192;
                const int pos  = flat % 192;
                const float4 v = *(const float4*)(&sStage[flat]);
                *(float4*)(&outp[(ebase + ch*4 + eloc) * (size_t)FEA + 64 + pos]) = v;
            }
            __syncthreads();   // drain complete before next ch overwrites
        }
    }
}

extern "C" void kernel_launch(void* const* d_in, const int* in_sizes, int n_in,
                              void* d_out, int out_size, void* d_ws, size_t ws_size,
                              hipStream_t stream) {
    (void)in_sizes; (void)n_in; (void)d_ws; (void)ws_size; (void)out_size;
    const float* fea_a = (const float*)d_in[0];
    const float* vec_a = (const float*)d_in[1];
    const float* len_a = (const float*)d_in[2];
    const float* W1_a  = (const float*)d_in[3];
    const float* b1_a  = (const float*)d_in[4];
    const float* g_a   = (const float*)d_in[5];
    const float* be_a  = (const float*)d_in[6];
    const float* W2_a  = (const float*)d_in[7];
    const float* fea_b = (const float*)d_in[8];
    const float* vec_b = (const float*)d_in[9];
    const float* len_b = (const float*)d_in[10];
    const float* W1_b  = (const float*)d_in[11];
    const float* b1_b  = (const float*)d_in[12];
    const float* g_b   = (const float*)d_in[13];
    const float* be_b  = (const float*)d_in[14];
    const float* W2_b  = (const float*)d_in[15];
    float* out = (float*)d_out;

    dim3 grid(E_N / EPB, 2);
    dim3 block(NT);
    hipLaunchKernelGGL(fused_mlp_dtp, grid, block, 0, stream,
                       fea_a, vec_a, len_a, W1_a, b1_a, g_a, be_a, W2_a,
                       fea_b, vec_b, len_b, W1_b, b1_b, g_b, be_b, W2_b,
                       out);
}